// Round 3
// baseline (271.061 us; speedup 1.0000x reference)
//
#include <hip/hip_runtime.h>
#include <stdint.h>

typedef unsigned short u16;
typedef __bf16 bf16x8 __attribute__((ext_vector_type(8)));
typedef float f32x4 __attribute__((ext_vector_type(4)));

#define MM 2
#define NN 8
#define CC 1024
#define DD 256
#define BB 32
#define SS 512

__device__ __forceinline__ u16 f2bf(float f) {
  uint32_t u = __float_as_uint(f);
  u += 0x7FFFu + ((u >> 16) & 1u);   // round-to-nearest-even
  return (u16)(u >> 16);
}

__device__ __forceinline__ uint32_t pack2(float a, float b) {
  return (uint32_t)f2bf(a) | ((uint32_t)f2bf(b) << 16);
}

__device__ __forceinline__ void async16(const void* g, void* l) {
  __builtin_amdgcn_global_load_lds(
      (const __attribute__((address_space(1))) uint32_t*)g,
      (__attribute__((address_space(3))) uint32_t*)l, 16, 0, 0);
}

__device__ __forceinline__ void packA(const float4& a, const float4& b, u16* dst) {
  *reinterpret_cast<uint4*>(dst) =
      make_uint4(pack2(a.x, a.y), pack2(a.z, a.w),
                 pack2(b.x, b.y), pack2(b.z, b.w));
}

// ---------------- prep: transpose+convert both weight tensors ----------------
// src fp32 [16][K][N] -> dst bf16 [16][N][K]; tile 64(K) x 32(N).
__global__ __launch_bounds__(256) void prep_w(
    const float* __restrict__ dw, u16* __restrict__ wdT,
    const float* __restrict__ uw, u16* __restrict__ wuT) {
  __shared__ float tile[64][33];
  int bid = blockIdx.x;
  const float* src; u16* dst; int K, N, tk, tn;
  if (bid < 2048) {
    K = CC; N = DD;
    const int slab = bid >> 7, t = bid & 127;   // 16 x 8 tiles per slab
    tk = t >> 3; tn = t & 7;
    src = dw + (size_t)slab * K * N;
    dst = wdT + (size_t)slab * K * N;
  } else {
    bid -= 2048;
    K = DD; N = CC;
    const int slab = bid >> 7, t = bid & 127;   // 4 x 32 tiles per slab
    tk = t >> 5; tn = t & 31;
    src = uw + (size_t)slab * K * N;
    dst = wuT + (size_t)slab * K * N;
  }
  const int k0 = tk * 64, n0 = tn * 32;
  const int tx = threadIdx.x & 31, ty = threadIdx.x >> 5;
#pragma unroll
  for (int i = 0; i < 64; i += 8)
    tile[ty + i][tx] = src[(size_t)(k0 + ty + i) * N + n0 + tx];
  __syncthreads();
  uint32_t* dst32 = reinterpret_cast<uint32_t*>(dst);
#pragma unroll
  for (int i = 0; i < 32; i += 8) {
    const int nr = ty + i;
    dst32[((size_t)(n0 + nr) * K + k0) / 2 + tx] =
        pack2(tile[2 * tx][nr], tile[2 * tx + 1][nr]);
  }
}

// ---------------- fused: u = silu(x@Wd + b) @ Wu, z kept in LDS -------------
// 128-row S-tiles: grid (4, 64) = 256 blocks (1/CU), 512 threads (8 waves).
// Pipeline: B via 3-slot LDS-DMA 2 iters ahead; A (x fp32) via register
// ping-pong 2 iters ahead (decouples x HBM latency from the per-iter FIFO
// wait); phase-2 waits are store-agnostic (vmcnt(63) on store-adjacent
// iters). All waits are count-proof: vmcnt(N) with N = #this-iter VMEM ops
// guarantees all prior-iter ops retired regardless of intra-iter order.
__global__ __launch_bounds__(512, 2) void fused_adapter(
    const float* __restrict__ x, const u16* __restrict__ wdT,
    const u16* __restrict__ wuT, const float* __restrict__ db,
    const int* __restrict__ eidx, float* __restrict__ out) {
  __shared__ __align__(16) u16 smA[2][128 * 32];   // 2 x  8 KB: x staging (bf16)
  __shared__ __align__(16) u16 smB[3][256 * 32];   // 3 x 16 KB: weight staging
  __shared__ __align__(16) u16 zl[8 * 128 * 32];   // 64 KB: z (8 k-tiles)

  const int pair = blockIdx.y;
  const int m = pair >> 5;
  const int b = pair & 31;
  const int e = eidx[pair];
  const int s0 = blockIdx.x * 128;

  const int tid = threadIdx.x;
  const int lane = tid & 63;
  const int wave = tid >> 6;          // 0..7
  const int quad = lane >> 4;
  const int l16 = lane & 15;
  const int fx = (l16 >> 1) & 3;      // frag-read slot swizzle

  const int wr = (wave >> 2) * 64;    // wave s-rows
  const int wc = (wave & 3) * 64;     // wave cols (d in ph1, c in ph2)

  const u16* Bd = wdT + (size_t)(m * NN + e) * DD * CC;   // [256 d x 1024 k]
  const u16* Bu = wuT + (size_t)(m * NN + e) * CC * DD;   // [1024 c x 256 k]

  const float* bias_p = db + (size_t)(m * NN + e) * DD;
  float biasr[4];
#pragma unroll
  for (int j = 0; j < 4; ++j) biasr[j] = bias_p[wc + j * 16 + l16];

  // A staging: thread covers row tid>>2, 16B chunk (tid&3) of the 64B row
  const int arow = tid >> 2;
  const int achk = tid & 3;
  const float* gAx = x + ((size_t)b * SS + s0 + arow) * CC + achk * 8;
  const int lAoff = arow * 32 + ((achk ^ ((arow >> 1) & 3)) * 8);

  // B staging: wave stages 32 rows (2 async16 of 16 rows); source pre-swizzled
  const int srow = lane >> 2;                       // 0..15
  const int qx = (lane & 3) ^ ((srow >> 1) & 3);    // swizzled source chunk
  const u16* gBd = Bd + (size_t)(wave * 32 + srow) * CC + qx * 8;
  const u16* gBu = Bu + (size_t)(wave * 32 + srow) * DD + qx * 8;
  const int lB0o = wave * 32 * 32;
  const int lB1o = lB0o + 16 * 32;

  f32x4 acc[4][4];
#pragma unroll
  for (int i = 0; i < 4; ++i)
#pragma unroll
    for (int j = 0; j < 4; ++j) acc[i][j] = (f32x4){0.f, 0.f, 0.f, 0.f};

  float4 rA0a, rA0b, rA1a, rA1b;      // A register ping-pong (2 iters deep)

  // ---- prologue: A(0) direct pack, B(0),B(1) asyncs, A(1) into regs ----
  {
    float4 a0 = *reinterpret_cast<const float4*>(gAx);
    float4 a1 = *reinterpret_cast<const float4*>(gAx + 4);
    async16(gBd, &smB[0][lB0o]);
    async16(gBd + 16 * CC, &smB[0][lB1o]);
    async16(gBd + 32, &smB[1][lB0o]);
    async16(gBd + 16 * CC + 32, &smB[1][lB1o]);
    rA1a = *reinterpret_cast<const float4*>(gAx + 32);
    rA1b = *reinterpret_cast<const float4*>(gAx + 36);
    packA(a0, a1, &smA[0][lAoff]);
  }
  asm volatile("s_waitcnt vmcnt(2) lgkmcnt(0)" ::: "memory");
  __builtin_amdgcn_s_barrier();

  // ---- phase 1: K = 1024, 32 iters; B(kk) in slot kk%3, A(kk) in smA[kk&1] ----
  int slot_c = 0;
#pragma unroll 2
  for (int kk = 0; kk < 32; ++kk) {
    const int slot = slot_c;
    const int nslot = slot >= 1 ? slot - 1 : 2;   // (kk+2)%3
    slot_c = slot < 2 ? slot + 1 : 0;

    if (kk < 30) {                     // A(kk+2) into regs, B(kk+2) asyncs
      const int ko = (kk + 2) * 32;
      if ((kk & 1) == 0) {
        rA0a = *reinterpret_cast<const float4*>(gAx + ko);
        rA0b = *reinterpret_cast<const float4*>(gAx + ko + 4);
      } else {
        rA1a = *reinterpret_cast<const float4*>(gAx + ko);
        rA1b = *reinterpret_cast<const float4*>(gAx + ko + 4);
      }
      async16(gBd + ko, &smB[nslot][lB0o]);
      async16(gBd + 16 * CC + ko, &smB[nslot][lB1o]);
    } else {                           // phase-2 tiles g = kk-30 (ct=0)
      const int gg = kk - 30;
      async16(gBu + gg * 32, &smB[nslot][lB0o]);
      async16(gBu + 16 * DD + gg * 32, &smB[nslot][lB1o]);
    }

    bf16x8 af[4], bfr[4];
#pragma unroll
    for (int i = 0; i < 4; ++i)
      af[i] = *reinterpret_cast<const bf16x8*>(
          &smA[kk & 1][(wr + i * 16 + l16) * 32 + (quad ^ fx) * 8]);
#pragma unroll
    for (int j = 0; j < 4; ++j)
      bfr[j] = *reinterpret_cast<const bf16x8*>(
          &smB[slot][(wc + j * 16 + l16) * 32 + (quad ^ fx) * 8]);
    __builtin_amdgcn_s_setprio(1);
#pragma unroll
    for (int i = 0; i < 4; ++i)
#pragma unroll
      for (int j = 0; j < 4; ++j)
        acc[i][j] = __builtin_amdgcn_mfma_f32_16x16x32_bf16(af[i], bfr[j], acc[i][j], 0, 0, 0);
    __builtin_amdgcn_s_setprio(0);

    if (kk < 31) {                     // pack A(kk+1), loaded 2 iters ago
      if ((kk & 1) == 0) packA(rA1a, rA1b, &smA[1][lAoff]);
      else               packA(rA0a, rA0b, &smA[0][lAoff]);
    }

    if (kk < 30) asm volatile("s_waitcnt vmcnt(4) lgkmcnt(0)" ::: "memory");
    else         asm volatile("s_waitcnt vmcnt(2) lgkmcnt(0)" ::: "memory");
    __builtin_amdgcn_s_barrier();
  }

  // ---- silu + bias, z -> LDS k-tile layout (swizzled) ----
#pragma unroll
  for (int j = 0; j < 4; ++j) {
    const int d = wc + j * 16 + l16;
    const int kt = d >> 5;
    const int kl = d & 31;
    const int slot0 = kl >> 3;
    const int kin = kl & 7;
#pragma unroll
    for (int i = 0; i < 4; ++i) {
      const int zr = wr + i * 16 + quad * 4;
#pragma unroll
      for (int r = 0; r < 4; ++r) {
        const int row = zr + r;
        float v = acc[i][j][r] + biasr[j];
        v = v / (1.f + __expf(-v));
        zl[kt * 4096 + row * 32 + ((slot0 ^ ((row >> 1) & 3)) * 8) + kin] = f2bf(v);
      }
    }
  }
  asm volatile("s_waitcnt vmcnt(2) lgkmcnt(0)" ::: "memory");  // Bu g0 landed
  __builtin_amdgcn_s_barrier();

  // ---- phase 2: 32 iters over (ct,it); tile g in slot (g+2)%3 ----
  float* ob = out + ((size_t)pair * SS + s0) * CC;

  int slot2_c = 2;
  for (int g = 0; g < 32; ++g) {
    const int slot = slot2_c;
    const int nslot = slot >= 1 ? slot - 1 : 2;
    slot2_c = slot < 2 ? slot + 1 : 0;
    const int ct = g >> 3;
    const int it = g & 7;
    if (g < 30) {
      const int g2 = g + 2;
      const size_t ro = (size_t)(g2 >> 3) * 256 * DD + (g2 & 7) * 32;
      async16(gBu + ro, &smB[nslot][lB0o]);
      async16(gBu + ro + 16 * DD, &smB[nslot][lB1o]);
    }
    if (it == 0) {
#pragma unroll
      for (int i = 0; i < 4; ++i)
#pragma unroll
        for (int j = 0; j < 4; ++j) acc[i][j] = (f32x4){0.f, 0.f, 0.f, 0.f};
    }
    bf16x8 af[4], bfr[4];
#pragma unroll
    for (int i = 0; i < 4; ++i)
      af[i] = *reinterpret_cast<const bf16x8*>(
          &zl[it * 4096 + (wr + i * 16 + l16) * 32 + (quad ^ fx) * 8]);
#pragma unroll
    for (int j = 0; j < 4; ++j)
      bfr[j] = *reinterpret_cast<const bf16x8*>(
          &smB[slot][(wc + j * 16 + l16) * 32 + (quad ^ fx) * 8]);
    __builtin_amdgcn_s_setprio(1);
#pragma unroll
    for (int i = 0; i < 4; ++i)
#pragma unroll
      for (int j = 0; j < 4; ++j)
        acc[i][j] = __builtin_amdgcn_mfma_f32_16x16x32_bf16(af[i], bfr[j], acc[i][j], 0, 0, 0);
    __builtin_amdgcn_s_setprio(0);
    if (it == 7) {
      asm volatile("" ::: "memory");   // pin issue order: asyncs before stores
#pragma unroll
      for (int j = 0; j < 4; ++j) {
        const int c = ct * 256 + wc + j * 16 + l16;
#pragma unroll
        for (int i = 0; i < 4; ++i) {
          const int sr = wr + i * 16 + quad * 4;
#pragma unroll
          for (int r = 0; r < 4; ++r)
            ob[(size_t)(sr + r) * CC + c] = acc[i][j][r];
        }
      }
    }
    if (g < 31) {
      if (g == 30)
        asm volatile("s_waitcnt vmcnt(0) lgkmcnt(0)" ::: "memory");
      else if (it == 7 || it == 0)   // store-adjacent: stores stay in flight
        asm volatile("s_waitcnt vmcnt(63) lgkmcnt(0)" ::: "memory");
      else
        asm volatile("s_waitcnt vmcnt(2) lgkmcnt(0)" ::: "memory");
      __builtin_amdgcn_s_barrier();
    }
  }
}

extern "C" void kernel_launch(void* const* d_in, const int* in_sizes, int n_in,
                              void* d_out, int out_size, void* d_ws, size_t ws_size,
                              hipStream_t stream) {
  const float* x  = (const float*)d_in[0];  // [B,S,C]
  const int* eidx = (const int*)d_in[1];    // [M,B]
  const float* dw = (const float*)d_in[2];  // [M,N,C,D]
  const float* db = (const float*)d_in[3];  // [M,N,D]
  const float* uw = (const float*)d_in[4];  // [M,N,D,C]
  float* out = (float*)d_out;               // [M,B,S,C]

  char* ws = (char*)d_ws;
  u16* wdT = (u16*)(ws);                                   //  8 MB: [M,N,D,C] bf16
  u16* wuT = (u16*)(ws + (size_t)8 * 1024 * 1024);         //  8 MB: [M,N,C,D] bf16

  prep_w<<<dim3(4096), dim3(256), 0, stream>>>(dw, wdT, uw, wuT);
  fused_adapter<<<dim3(SS / 128, MM * BB), dim3(512), 0, stream>>>(
      x, wdT, wuT, db, eidx, out);
}

// Round 4
// 247.314 us; speedup vs baseline: 1.0960x; 1.0960x over previous
//
#include <hip/hip_runtime.h>
#include <stdint.h>

typedef unsigned short u16;
typedef __bf16 bf16x8 __attribute__((ext_vector_type(8)));
typedef float f32x4 __attribute__((ext_vector_type(4)));

#define MM 2
#define NN 8
#define CC 1024
#define DD 256
#define BB 32
#define SS 512

__device__ __forceinline__ u16 f2bf(float f) {
  uint32_t u = __float_as_uint(f);
  u += 0x7FFFu + ((u >> 16) & 1u);   // round-to-nearest-even
  return (u16)(u >> 16);
}

__device__ __forceinline__ uint32_t pack2(float a, float b) {
  return (uint32_t)f2bf(a) | ((uint32_t)f2bf(b) << 16);
}

__device__ __forceinline__ void async16(const void* g, void* l) {
  __builtin_amdgcn_global_load_lds(
      (const __attribute__((address_space(1))) uint32_t*)g,
      (__attribute__((address_space(3))) uint32_t*)l, 16, 0, 0);
}

// ---------------- prep: transpose+convert both weight tensors ----------------
// src fp32 [16][K][N] -> dst bf16 [16][N][K]; tile 64(K) x 32(N).
__global__ __launch_bounds__(256) void prep_w(
    const float* __restrict__ dw, u16* __restrict__ wdT,
    const float* __restrict__ uw, u16* __restrict__ wuT) {
  __shared__ float tile[64][33];
  int bid = blockIdx.x;
  const float* src; u16* dst; int K, N, tk, tn;
  if (bid < 2048) {
    K = CC; N = DD;
    const int slab = bid >> 7, t = bid & 127;   // 16 x 8 tiles per slab
    tk = t >> 3; tn = t & 7;
    src = dw + (size_t)slab * K * N;
    dst = wdT + (size_t)slab * K * N;
  } else {
    bid -= 2048;
    K = DD; N = CC;
    const int slab = bid >> 7, t = bid & 127;   // 4 x 32 tiles per slab
    tk = t >> 5; tn = t & 31;
    src = uw + (size_t)slab * K * N;
    dst = wuT + (size_t)slab * K * N;
  }
  const int k0 = tk * 64, n0 = tn * 32;
  const int tx = threadIdx.x & 31, ty = threadIdx.x >> 5;
#pragma unroll
  for (int i = 0; i < 64; i += 8)
    tile[ty + i][tx] = src[(size_t)(k0 + ty + i) * N + n0 + tx];
  __syncthreads();
  uint32_t* dst32 = reinterpret_cast<uint32_t*>(dst);
#pragma unroll
  for (int i = 0; i < 32; i += 8) {
    const int nr = ty + i;
    dst32[((size_t)(n0 + nr) * K + k0) / 2 + tx] =
        pack2(tile[2 * tx][nr], tile[2 * tx + 1][nr]);
  }
}

// ---------------- fused: u = silu(x@Wd + b) @ Wu, z kept in LDS -------------
// 128-row S-tiles, BK=64: 16 + 16 barrier-iterations (was 32+32) to halve the
// fixed per-iteration barrier/convoy cost that r0-r3 showed is insensitive to
// vmcnt scheduling. LDS = 160 KB exactly (smA 2x16K, smB 2x32K, zl 64K).
// B/A tiles are [row][64k] with 8-chunk XOR swizzle (chunk ^= row&7): DMA dest
// linear, global source pre-swizzled, frag reads apply the same involution
// (16-lane frag read -> 2-way bank aliasing = free).
__global__ __launch_bounds__(512, 2) void fused_adapter(
    const float* __restrict__ x, const u16* __restrict__ wdT,
    const u16* __restrict__ wuT, const float* __restrict__ db,
    const int* __restrict__ eidx, float* __restrict__ out) {
  __shared__ __align__(16) u16 smA[2][128 * 64];   // 2 x 16 KB: x staging (bf16)
  __shared__ __align__(16) u16 smB[2][256 * 64];   // 2 x 32 KB: weight staging
  __shared__ __align__(16) u16 zl[8 * 128 * 32];   // 64 KB: z (8 k-tiles)

  const int pair = blockIdx.y;
  const int m = pair >> 5;
  const int b = pair & 31;
  const int e = eidx[pair];
  const int s0 = blockIdx.x * 128;

  const int tid = threadIdx.x;
  const int lane = tid & 63;
  const int wave = tid >> 6;          // 0..7
  const int quad = lane >> 4;
  const int l16 = lane & 15;
  const int fx = (l16 >> 1) & 3;      // zl slot swizzle (16B slots in 32-k rows)
  const int fxr = l16 & 7;            // smA/smB chunk swizzle (8 chunks / 64-k row)

  const int wr = (wave >> 2) * 64;    // wave s-rows
  const int wc = (wave & 3) * 64;     // wave cols (d in ph1, c in ph2)

  const u16* Bd = wdT + (size_t)(m * NN + e) * DD * CC;   // [256 d x 1024 k]
  const u16* Bu = wuT + (size_t)(m * NN + e) * CC * DD;   // [1024 c x 256 k]

  const float* bias_p = db + (size_t)(m * NN + e) * DD;
  float biasr[4];
#pragma unroll
  for (int j = 0; j < 4; ++j) biasr[j] = bias_p[wc + j * 16 + l16];

  // A staging: thread covers row tid>>2, chunks (tid&3) and (tid&3)+4 of 8
  const int arow = tid >> 2;
  const int c0 = tid & 3;
  const float* gAx = x + ((size_t)b * SS + s0 + arow) * CC;
  const int lA0 = arow * 64 + ((c0 ^ (arow & 7)) * 8);
  const int lA1 = arow * 64 + (((c0 + 4) ^ (arow & 7)) * 8);

  // B staging: 4 async16/wave/iter; 8 lanes per row, source chunk pre-swizzled
  const int r_l = lane >> 3;          // 0..7: row within 8-row group
  const int sx = (lane & 7) ^ r_l;    // pre-swizzled source chunk

  f32x4 acc[4][4];
#pragma unroll
  for (int i = 0; i < 4; ++i)
#pragma unroll
    for (int j = 0; j < 4; ++j) acc[i][j] = (f32x4){0.f, 0.f, 0.f, 0.f};

  // ---- prologue: A(0) direct pack, B(0) asyncs ----
  {
    float4 a0 = *reinterpret_cast<const float4*>(gAx + c0 * 8);
    float4 a1 = *reinterpret_cast<const float4*>(gAx + c0 * 8 + 4);
    float4 a2 = *reinterpret_cast<const float4*>(gAx + (c0 + 4) * 8);
    float4 a3 = *reinterpret_cast<const float4*>(gAx + (c0 + 4) * 8 + 4);
#pragma unroll
    for (int s = 0; s < 4; ++s)
      async16(Bd + (size_t)(wave * 32 + s * 8 + r_l) * CC + sx * 8,
              &smB[0][(wave * 32 + s * 8) * 64]);
    *reinterpret_cast<uint4*>(&smA[0][lA0]) =
        make_uint4(pack2(a0.x, a0.y), pack2(a0.z, a0.w),
                   pack2(a1.x, a1.y), pack2(a1.z, a1.w));
    *reinterpret_cast<uint4*>(&smA[0][lA1]) =
        make_uint4(pack2(a2.x, a2.y), pack2(a2.z, a2.w),
                   pack2(a3.x, a3.y), pack2(a3.z, a3.w));
  }
  asm volatile("s_waitcnt vmcnt(0) lgkmcnt(0)" ::: "memory");
  __builtin_amdgcn_s_barrier();

  // ---- phase 1: K = 1024, 16 iters of BK=64 ----
  for (int kk = 0; kk < 16; ++kk) {
    const int cur = kk & 1, nxt = cur ^ 1;
    float4 a0, a1, a2, a3;
    if (kk < 15) {                     // A(kk+1) loads first (retire before asyncs)
      const float* gA = gAx + (kk + 1) * 64;
      a0 = *reinterpret_cast<const float4*>(gA + c0 * 8);
      a1 = *reinterpret_cast<const float4*>(gA + c0 * 8 + 4);
      a2 = *reinterpret_cast<const float4*>(gA + (c0 + 4) * 8);
      a3 = *reinterpret_cast<const float4*>(gA + (c0 + 4) * 8 + 4);
      const int ko = (kk + 1) * 64;
#pragma unroll
      for (int s = 0; s < 4; ++s)
        async16(Bd + (size_t)(wave * 32 + s * 8 + r_l) * CC + ko + sx * 8,
                &smB[nxt][(wave * 32 + s * 8) * 64]);
    } else {                           // stage phase-2 g=0 tile (ct=0, k=0..63)
#pragma unroll
      for (int s = 0; s < 4; ++s)
        async16(Bu + (size_t)(wave * 32 + s * 8 + r_l) * DD + sx * 8,
                &smB[nxt][(wave * 32 + s * 8) * 64]);
    }
#pragma unroll
    for (int h = 0; h < 2; ++h) {
      bf16x8 af[4], bfr[4];
#pragma unroll
      for (int i = 0; i < 4; ++i)
        af[i] = *reinterpret_cast<const bf16x8*>(
            &smA[cur][(wr + i * 16 + l16) * 64 + ((h * 4 + quad) ^ fxr) * 8]);
#pragma unroll
      for (int j = 0; j < 4; ++j)
        bfr[j] = *reinterpret_cast<const bf16x8*>(
            &smB[cur][(wc + j * 16 + l16) * 64 + ((h * 4 + quad) ^ fxr) * 8]);
      __builtin_amdgcn_s_setprio(1);
#pragma unroll
      for (int i = 0; i < 4; ++i)
#pragma unroll
        for (int j = 0; j < 4; ++j)
          acc[i][j] = __builtin_amdgcn_mfma_f32_16x16x32_bf16(af[i], bfr[j], acc[i][j], 0, 0, 0);
      __builtin_amdgcn_s_setprio(0);
    }
    if (kk < 15) {                     // pack A(kk+1)
      *reinterpret_cast<uint4*>(&smA[nxt][lA0]) =
          make_uint4(pack2(a0.x, a0.y), pack2(a0.z, a0.w),
                     pack2(a1.x, a1.y), pack2(a1.z, a1.w));
      *reinterpret_cast<uint4*>(&smA[nxt][lA1]) =
          make_uint4(pack2(a2.x, a2.y), pack2(a2.z, a2.w),
                     pack2(a3.x, a3.y), pack2(a3.z, a3.w));
    }
    asm volatile("s_waitcnt vmcnt(0) lgkmcnt(0)" ::: "memory");
    __builtin_amdgcn_s_barrier();
  }

  // ---- silu + bias, z -> LDS k-tile layout (old zl swizzle, unchanged) ----
#pragma unroll
  for (int j = 0; j < 4; ++j) {
    const int d = wc + j * 16 + l16;
    const int kt = d >> 5;
    const int kl = d & 31;
    const int slot0 = kl >> 3;
    const int kin = kl & 7;
#pragma unroll
    for (int i = 0; i < 4; ++i) {
      const int zr = wr + i * 16 + quad * 4;
#pragma unroll
      for (int r = 0; r < 4; ++r) {
        const int row = zr + r;
        float v = acc[i][j][r] + biasr[j];
        v = v / (1.f + __expf(-v));
        zl[kt * 4096 + row * 32 + ((slot0 ^ ((row >> 1) & 3)) * 8) + kin] = f2bf(v);
      }
    }
  }
  asm volatile("s_waitcnt lgkmcnt(0)" ::: "memory");
  __builtin_amdgcn_s_barrier();

  // ---- phase 2: 16 iters of BK=64 over (ct, it2) ----
  float* ob = out + ((size_t)pair * SS + s0) * CC;

  for (int g = 0; g < 16; ++g) {
    const int cur2 = g & 1, nxt2 = cur2 ^ 1;
    const int ct = g >> 2;
    const int it2 = g & 3;
    if (g < 15) {
      const int g2 = g + 1;
      const size_t ro = (size_t)(g2 >> 2) * 256 * DD + (g2 & 3) * 64;
#pragma unroll
      for (int s = 0; s < 4; ++s)
        async16(Bu + ro + (size_t)(wave * 32 + s * 8 + r_l) * DD + sx * 8,
                &smB[nxt2][(wave * 32 + s * 8) * 64]);
    }
    if (it2 == 0) {
#pragma unroll
      for (int i = 0; i < 4; ++i)
#pragma unroll
        for (int j = 0; j < 4; ++j) acc[i][j] = (f32x4){0.f, 0.f, 0.f, 0.f};
    }
#pragma unroll
    for (int h = 0; h < 2; ++h) {
      bf16x8 af[4], bfr[4];
#pragma unroll
      for (int i = 0; i < 4; ++i)
        af[i] = *reinterpret_cast<const bf16x8*>(
            &zl[(it2 * 2 + h) * 4096 + (wr + i * 16 + l16) * 32 + (quad ^ fx) * 8]);
#pragma unroll
      for (int j = 0; j < 4; ++j)
        bfr[j] = *reinterpret_cast<const bf16x8*>(
            &smB[cur2][(wc + j * 16 + l16) * 64 + ((h * 4 + quad) ^ fxr) * 8]);
      __builtin_amdgcn_s_setprio(1);
#pragma unroll
      for (int i = 0; i < 4; ++i)
#pragma unroll
        for (int j = 0; j < 4; ++j)
          acc[i][j] = __builtin_amdgcn_mfma_f32_16x16x32_bf16(af[i], bfr[j], acc[i][j], 0, 0, 0);
      __builtin_amdgcn_s_setprio(0);
    }
    if (it2 == 3) {
#pragma unroll
      for (int j = 0; j < 4; ++j) {
        const int c = ct * 256 + wc + j * 16 + l16;
#pragma unroll
        for (int i = 0; i < 4; ++i) {
          const int sr = wr + i * 16 + quad * 4;
#pragma unroll
          for (int r = 0; r < 4; ++r)
            ob[(size_t)(sr + r) * CC + c] = acc[i][j][r];
        }
      }
    }
    if (g < 15) {
      asm volatile("s_waitcnt vmcnt(0) lgkmcnt(0)" ::: "memory");
      __builtin_amdgcn_s_barrier();
    }
  }
}

extern "C" void kernel_launch(void* const* d_in, const int* in_sizes, int n_in,
                              void* d_out, int out_size, void* d_ws, size_t ws_size,
                              hipStream_t stream) {
  const float* x  = (const float*)d_in[0];  // [B,S,C]
  const int* eidx = (const int*)d_in[1];    // [M,B]
  const float* dw = (const float*)d_in[2];  // [M,N,C,D]
  const float* db = (const float*)d_in[3];  // [M,N,D]
  const float* uw = (const float*)d_in[4];  // [M,N,D,C]
  float* out = (float*)d_out;               // [M,B,S,C]

  char* ws = (char*)d_ws;
  u16* wdT = (u16*)(ws);                                   //  8 MB: [M,N,D,C] bf16
  u16* wuT = (u16*)(ws + (size_t)8 * 1024 * 1024);         //  8 MB: [M,N,C,D] bf16

  prep_w<<<dim3(4096), dim3(256), 0, stream>>>(dw, wdT, uw, wuT);
  fused_adapter<<<dim3(SS / 128, MM * BB), dim3(512), 0, stream>>>(
      x, wdT, wuT, db, eidx, out);
}